// Round 15
// baseline (287.453 us; speedup 1.0000x reference)
//
#include <hip/hip_runtime.h>

#define NN 50000
#define MPAD 50048   // 1564 * 32, padded row count for 32-row GEMM tiles

typedef unsigned short u16;
typedef unsigned int u32;
typedef unsigned char u8;
typedef short s16x8 __attribute__((ext_vector_type(8)));   // 8 bf16 (4 VGPRs)
typedef float f32x4 __attribute__((ext_vector_type(4)));
typedef float f32x2 __attribute__((ext_vector_type(2)));

__device__ inline u16 f2bf(float f) {
    u32 u = __float_as_uint(f);
    u32 r = (u + 0x7FFF + ((u >> 16) & 1)) >> 16;   // RNE
    return (u16)r;
}
__device__ inline float bf2f(u16 s) { return __uint_as_float(((u32)s) << 16); }

// ---- fp8 e4m3 helpers (hw cvt on gfx950; manual fallback) ----
#if __has_builtin(__builtin_amdgcn_cvt_pk_f32_fp8) && __has_builtin(__builtin_amdgcn_cvt_pk_fp8_f32)
#define HW_FP8 1
#endif

__device__ inline float fp8_dec1(u32 b) {   // manual e4m3fn -> f32
    u32 s = (b >> 7) & 1, e = (b >> 3) & 15, m = b & 7;
    float mag = e ? __uint_as_float(((e + 120) << 23) | (m << 20))
                  : (float)m * 0.001953125f;
    return s ? -mag : mag;
}
__device__ inline u8 fp8_enc1(float f) {    // manual f32 -> e4m3fn (RNE)
    u32 u = __float_as_uint(f);
    u32 s = (u >> 31) << 7;
    float a = fabsf(f);
    if (a >= 448.f) return (u8)(s | 0x7E);
    if (a < 0.015625f) {
        u32 m = (u32)__float2int_rn(a * 512.f);
        return (u8)(s | m);
    }
    u32 au = __float_as_uint(a);
    u32 r = au + 0x7FFFF + ((au >> 20) & 1);
    u32 e = (r >> 23) - 120;
    u32 m = (r >> 20) & 7;
    return (u8)(s | (e << 3) | m);
}

__device__ inline void fp8x4_acc(u32 v, float* acc) {
#ifdef HW_FP8
    f32x2 lo = __builtin_amdgcn_cvt_pk_f32_fp8(v, false);
    f32x2 hi = __builtin_amdgcn_cvt_pk_f32_fp8(v, true);
    acc[0] += lo[0]; acc[1] += lo[1]; acc[2] += hi[0]; acc[3] += hi[1];
#else
    acc[0] += fp8_dec1(v & 0xFF);
    acc[1] += fp8_dec1((v >> 8) & 0xFF);
    acc[2] += fp8_dec1((v >> 16) & 0xFF);
    acc[3] += fp8_dec1(v >> 24);
#endif
}
__device__ inline void fp8x2_acc(u32 v, float* acc) {
#ifdef HW_FP8
    f32x2 lo = __builtin_amdgcn_cvt_pk_f32_fp8(v, false);
    acc[0] += lo[0]; acc[1] += lo[1];
#else
    acc[0] += fp8_dec1(v & 0xFF);
    acc[1] += fp8_dec1((v >> 8) & 0xFF);
#endif
}
__device__ inline u32 f32x4_to_fp8(float a, float b, float c, float d) {
#ifdef HW_FP8
    u32 lo = (u32)__builtin_amdgcn_cvt_pk_fp8_f32(a, b, 0, false) & 0xFFFF;
    u32 hi = (u32)__builtin_amdgcn_cvt_pk_fp8_f32(c, d, 0, false) & 0xFFFF;
    return lo | (hi << 16);
#else
    return (u32)fp8_enc1(a) | ((u32)fp8_enc1(b) << 8) |
           ((u32)fp8_enc1(c) << 16) | ((u32)fp8_enc1(d) << 24);
#endif
}

template <typename T>
__device__ inline const __attribute__((address_space(1))) T* as_g(const T* p) {
    return (const __attribute__((address_space(1))) T*)p;
}
template <typename T>
__device__ inline __attribute__((address_space(3))) T* as_l(T* p) {
    return (__attribute__((address_space(3))) T*)p;
}

// ---------------- degree count ----------------
__global__ void k_count(const int* __restrict__ dst, int E, int* __restrict__ deg) {
    int i = blockIdx.x * blockDim.x + threadIdx.x;
    if (i < E) atomicAdd(&deg[dst[i]], 1);
}

// ---------------- CSR scans ----------------
__global__ void k_scan1(const int* __restrict__ deg, int n,
                        int* __restrict__ out, int* __restrict__ bsum) {
    __shared__ int s[256];
    int t = threadIdx.x;
    int base = blockIdx.x * 1024;
    int v[4]; int sum = 0;
#pragma unroll
    for (int r = 0; r < 4; r++) {
        int idx = base + t * 4 + r;
        v[r] = (idx < n) ? deg[idx] : 0;
        sum += v[r];
    }
    s[t] = sum; __syncthreads();
    for (int off = 1; off < 256; off <<= 1) {
        int x = (t >= off) ? s[t - off] : 0;
        __syncthreads();
        s[t] += x;
        __syncthreads();
    }
    int excl = s[t] - sum;
    if (t == 255) bsum[blockIdx.x] = s[255];
    int run = excl;
#pragma unroll
    for (int r = 0; r < 4; r++) {
        int idx = base + t * 4 + r;
        if (idx < n) out[idx] = run;
        run += v[r];
    }
}

__global__ void k_scan2(int* __restrict__ bsum, int nb) {
    __shared__ int s[64];
    int t = threadIdx.x;
    int orig = (t < nb) ? bsum[t] : 0;
    s[t] = orig; __syncthreads();
    for (int off = 1; off < 64; off <<= 1) {
        int x = (t >= off) ? s[t - off] : 0;
        __syncthreads();
        s[t] += x;
        __syncthreads();
    }
    if (t < nb) bsum[t] = s[t] - orig;
}

__global__ void k_scan3(int* __restrict__ rowptr, const int* __restrict__ bsum,
                        int n, int E) {
    int i = blockIdx.x * blockDim.x + threadIdx.x;
    if (i < n) rowptr[i] += bsum[i >> 10];
    if (i == 0) rowptr[n] = E;
}

// ------ fill + castx + wpack in ONE launch; col entries are u16 ------
__device__ inline void wpack_body(int idx, const float* __restrict__ Wl,
                                  const float* __restrict__ Wr, int K,
                                  u16* __restrict__ Wp) {
    int KC = 2 * K;
    if (idx >= 256 * KC) return;
    int j = idx & 7;
    int l = (idx >> 3) & 63;
    int c = (idx >> 9) & 15;
    int q = idx >> 13;
    int n = c * 16 + (l & 15);
    int k = q * 32 + (l >> 4) * 8 + j;
    float v = (k < K) ? Wl[(size_t)k * 256 + n] : Wr[(size_t)(k - K) * 256 + n];
    Wp[idx] = f2bf(v);
}

#define FILL_BLOCKS ((800000 + 255) / 256)            // 3125
#define CASTX_BLOCKS (MPAD * 128 / 4 / 256)           // 6256
#define FCW_CAST_OFF FILL_BLOCKS
#define FCW_W0_OFF (FCW_CAST_OFF + CASTX_BLOCKS)
#define FCW_W1_OFF (FCW_W0_OFF + 256)
#define FCW_W2_OFF (FCW_W1_OFF + 512)
#define FCW_TOTAL (FCW_W2_OFF + 512)

__global__ void k_fcw(const int* __restrict__ dst, const int* __restrict__ src,
                      int E, const int* __restrict__ rowptr, int* __restrict__ deg,
                      u16* __restrict__ col,
                      const float* __restrict__ x, u16* __restrict__ xb,
                      u8* __restrict__ x8,
                      const float* __restrict__ Wl0, const float* __restrict__ Wr0,
                      u16* __restrict__ Wp0,
                      const float* __restrict__ Wl1, const float* __restrict__ Wr1,
                      u16* __restrict__ Wp1,
                      const float* __restrict__ Wl2, const float* __restrict__ Wr2,
                      u16* __restrict__ Wp2) {
    int b = blockIdx.x;
    if (b < FILL_BLOCKS) {
        int e = b * 256 + threadIdx.x;
        if (e < E) {
            int d = dst[e];
            int p = atomicAdd(&deg[d], -1) - 1;   // deg counts down; destroys deg
            col[rowptr[d] + p] = (u16)src[e];
        }
    } else if (b < FCW_W0_OFF) {
        int i = (b - FCW_CAST_OFF) * 256 + threadIdx.x;
        int idx = i * 4;
        u32 lo = 0, hi = 0, p8 = 0;
        if (idx < NN * 128) {
            float4 v = *reinterpret_cast<const float4*>(x + idx);
            lo = (u32)f2bf(v.x) | ((u32)f2bf(v.y) << 16);
            hi = (u32)f2bf(v.z) | ((u32)f2bf(v.w) << 16);
            p8 = f32x4_to_fp8(v.x, v.y, v.z, v.w);
        }
        uint2 o; o.x = lo; o.y = hi;
        *reinterpret_cast<uint2*>(xb + idx) = o;
        *reinterpret_cast<u32*>(x8 + idx) = p8;
    } else if (b < FCW_W1_OFF) {
        wpack_body((b - FCW_W0_OFF) * 256 + threadIdx.x, Wl0, Wr0, 128, Wp0);
    } else if (b < FCW_W2_OFF) {
        wpack_body((b - FCW_W1_OFF) * 256 + threadIdx.x, Wl1, Wr1, 256, Wp1);
    } else {
        wpack_body((b - FCW_W2_OFF) * 256 + threadIdx.x, Wl2, Wr2, 256, Wp2);
    }
}

// -------- aggregation (segment mean): fp8 gather -> bf16 out, u16 col --------
template <int D>
__global__ __launch_bounds__(256) void k_agg8(
    const u8* __restrict__ H8, const int* __restrict__ rowptr,
    const u16* __restrict__ col, u16* __restrict__ out) {
    constexpr int PER = D / 64;    // 2 or 4
    int wv = threadIdx.x >> 6, l = threadIdx.x & 63;
    int node = blockIdx.x * 4 + wv;
    if (node >= MPAD) return;
    size_t obase = (size_t)node * D + l * PER;
    if (node >= NN) {
        if (PER == 2) *reinterpret_cast<u32*>(out + obase) = 0;
        else { uint2 z; z.x = 0; z.y = 0; *reinterpret_cast<uint2*>(out + obase) = z; }
        return;
    }
    int beg = rowptr[node], end = rowptr[node + 1];
    float acc[PER];
#pragma unroll
    for (int j = 0; j < PER; j++) acc[j] = 0.f;

    int c = beg;
    if (PER == 4) {
        const int fo = l * 4;
        for (; c + 8 <= end; c += 8) {
            u32 v[8];
#pragma unroll
            for (int u = 0; u < 8; ++u)
                v[u] = *reinterpret_cast<const u32*>(H8 + (size_t)col[c + u] * D + fo);
#pragma unroll
            for (int u = 0; u < 8; ++u) fp8x4_acc(v[u], acc);
        }
        for (; c < end; ++c) {
            u32 v = *reinterpret_cast<const u32*>(H8 + (size_t)col[c] * D + fo);
            fp8x4_acc(v, acc);
        }
    } else {
        const int fo = l * 2;
        for (; c + 8 <= end; c += 8) {
            u16 v[8];
#pragma unroll
            for (int u = 0; u < 8; ++u)
                v[u] = *reinterpret_cast<const u16*>(H8 + (size_t)col[c + u] * D + fo);
#pragma unroll
            for (int u = 0; u < 8; ++u) fp8x2_acc((u32)v[u], acc);
        }
        for (; c < end; ++c) {
            u16 v = *reinterpret_cast<const u16*>(H8 + (size_t)col[c] * D + fo);
            fp8x2_acc((u32)v, acc);
        }
    }
    float inv = 1.f / fmaxf((float)(end - beg), 1.f);
    if (PER == 2) {
        u32 o = (u32)f2bf(acc[0] * inv) | ((u32)f2bf(acc[1] * inv) << 16);
        *reinterpret_cast<u32*>(out + obase) = o;
    } else {
        uint2 o;
        o.x = (u32)f2bf(acc[0] * inv) | ((u32)f2bf(acc[1] * inv) << 16);
        o.y = (u32)f2bf(acc[2] * inv) | ((u32)f2bf(acc[3] * inv) << 16);
        *reinterpret_cast<uint2*>(out + obase) = o;
    }
}

// ---------------- MFMA GEMM: single-barrier full-panel staging ----------------
// BM=32. The WHOLE A panel (NSTEP x 4KB tiles, 16/32KB) is staged to LDS with
// NSTEP global_load_lds per thread (FIFO), ONE __syncthreads (one vmcnt drain),
// then the MFMA loop runs with ZERO barriers: per-step ds_read of A fragments
// + reg-double-buffered B fragment loads. One HBM-latency exposure per block
// instead of NSTEP. Epilogue LDS unions onto the A panel (barrier before reuse).
template <int K, int MODE>   // MODE 0: relu -> bf16+fp8; MODE 1: JK-max -> f32
__global__ __launch_bounds__(256) void k_mgemm(
    const u16* __restrict__ Aagg, const u16* __restrict__ Ah,
    const u16* __restrict__ Wp, const float* __restrict__ bias,
    const u16* __restrict__ h1b, const u16* __restrict__ h2b,
    u16* __restrict__ outb, u8* __restrict__ out8, float* __restrict__ outf) {
    constexpr int KC = 2 * K;
    constexpr int NSTEP = KC / 64;     // 4 or 8, always even
    constexpr int SMEM = (NSTEP * 4096 > 16896) ? NSTEP * 4096 : 16896;
    __shared__ char smem[SMEM];        // A panel, later reused as epilogue stage
    int tid = threadIdx.x;
    int w = tid >> 6, l = tid & 63;
    int row0 = blockIdx.x * 32;
    int lr = l & 15, lk = l >> 4;

    f32x4 acc[2][4];
#pragma unroll
    for (int m = 0; m < 2; m++)
#pragma unroll
        for (int n = 0; n < 4; n++) acc[m][n] = (f32x4){0.f, 0.f, 0.f, 0.f};

    // stage ALL A tiles up front (FIFO; drained once by the barrier)
    {
        int r = tid >> 3, c = tid & 7;       // 32 rows x 8 chunks
        int g = c ^ (r & 7);
#pragma unroll
        for (int st = 0; st < NSTEP; ++st) {
            int kk = st * 64;
            const u16* Ab = (kk < K) ? Aagg : Ah;
            int koff = (kk < K) ? kk : kk - K;
            const u16* ga = Ab + (size_t)(row0 + r) * K + koff + g * 8;
            u16* lb = reinterpret_cast<u16*>(smem + st * 4096) + (size_t)(tid & ~63) * 8;
            __builtin_amdgcn_global_load_lds(as_g(ga), as_l(lb), 16, 0, 0);
        }
    }

    auto loadB = [&](s16x8 (&bv)[2][4], int st) {
#pragma unroll
        for (int kk2 = 0; kk2 < 2; ++kk2) {
            int q = st * 2 + kk2;
#pragma unroll
            for (int n = 0; n < 4; ++n) {
                const u16* gb = Wp + ((size_t)(q * 16 + w * 4 + n) * 64 + l) * 8;
                bv[kk2][n] = *reinterpret_cast<const s16x8*>(gb);
            }
        }
    };

    auto dostep = [&](int st, s16x8 (&bvUse)[2][4]) {
        const char* sAb = smem + st * 4096;
#pragma unroll
        for (int kk2 = 0; kk2 < 2; ++kk2) {
            s16x8 av[2];
#pragma unroll
            for (int m = 0; m < 2; ++m) {
                int off = (m * 16 + lr) * 128 + (((kk2 * 4 + lk) ^ (lr & 7)) << 4);
                av[m] = *reinterpret_cast<const s16x8*>(sAb + off);
            }
#pragma unroll
            for (int m = 0; m < 2; ++m)
#pragma unroll
                for (int n = 0; n < 4; ++n)
                    acc[m][n] = __builtin_amdgcn_mfma_f32_16x16x32_bf16(
                        av[m], bvUse[kk2][n], acc[m][n], 0, 0, 0);
        }
    };

    s16x8 bv0[2][4], bv1[2][4];
    loadB(bv0, 0);
    __syncthreads();                    // ONE drain: panel staged, bv0 in regs

#pragma unroll
    for (int st = 0; st < NSTEP; st += 2) {
        loadB(bv1, st + 1);             // prefetch next B (no barrier in the way)
        dostep(st, bv0);
        if (st + 2 < NSTEP) loadB(bv0, st + 2);
        dostep(st + 1, bv1);
    }

    float bb[4];
#pragma unroll
    for (int n = 0; n < 4; ++n) bb[n] = bias[w * 64 + n * 16 + lr];

    __syncthreads();                    // all ds_reads done before smem reuse

    if (MODE == 0) {
        u16* sE = (u16*)smem;              // [32][264] bf16, padded stride
#pragma unroll
        for (int m = 0; m < 2; ++m)
#pragma unroll
            for (int n = 0; n < 4; ++n) {
                int colx = w * 64 + n * 16 + lr;
#pragma unroll
                for (int i = 0; i < 4; ++i) {
                    int row = m * 16 + lk * 4 + i;
                    float z = fmaxf(acc[m][n][i] + bb[n], 0.f);
                    sE[row * 264 + colx] = f2bf(z);
                }
            }
        __syncthreads();
#pragma unroll
        for (int j = 0; j < 4; ++j) {
            int idx = j * 256 + tid;
            int r = idx >> 5;              // 0..31
            int cp = (idx & 31) * 8;       // col start (8 bf16 = 16B)
            uint4 v = *reinterpret_cast<const uint4*>(sE + r * 264 + cp);
            size_t go = (size_t)(row0 + r) * 256 + cp;
            *reinterpret_cast<uint4*>(outb + go) = v;
            u32 l8 = f32x4_to_fp8(bf2f((u16)(v.x & 0xFFFF)), bf2f((u16)(v.x >> 16)),
                                  bf2f((u16)(v.y & 0xFFFF)), bf2f((u16)(v.y >> 16)));
            u32 h8 = f32x4_to_fp8(bf2f((u16)(v.z & 0xFFFF)), bf2f((u16)(v.z >> 16)),
                                  bf2f((u16)(v.w & 0xFFFF)), bf2f((u16)(v.w >> 16)));
            uint2 o8; o8.x = l8; o8.y = h8;
            *reinterpret_cast<uint2*>(out8 + go) = o8;
        }
    } else {
        float* sEf = (float*)smem;         // [16][260] f32 per half-tile
#pragma unroll
        for (int m = 0; m < 2; ++m) {
#pragma unroll
            for (int n = 0; n < 4; ++n) {
                int colx = w * 64 + n * 16 + lr;
#pragma unroll
                for (int i = 0; i < 4; ++i) {
                    int row = row0 + m * 16 + lk * 4 + i;
                    size_t o = (size_t)row * 256 + colx;
                    float z = acc[m][n][i] + bb[n];
                    z = fmaxf(z, fmaxf(bf2f(h1b[o]), bf2f(h2b[o])));
                    sEf[(lk * 4 + i) * 260 + colx] = z;
                }
            }
            __syncthreads();
#pragma unroll
            for (int j = 0; j < 4; ++j) {
                int idx = j * 256 + tid;
                int r = idx >> 6;          // 0..15
                int cp = (idx & 63) * 4;   // 4 floats = 16B
                int grow = row0 + m * 16 + r;
                if (grow < NN) {
                    uint4 v = *reinterpret_cast<const uint4*>(sEf + r * 260 + cp);
                    *reinterpret_cast<uint4*>(outf + (size_t)grow * 256 + cp) = v;
                }
            }
            __syncthreads();               // WAR before next half-tile
        }
    }
}

extern "C" void kernel_launch(void* const* d_in, const int* in_sizes, int n_in,
                              void* d_out, int out_size, void* d_ws, size_t ws_size,
                              hipStream_t stream) {
    const float* x   = (const float*)d_in[0];
    const int*   ei  = (const int*)d_in[1];
    const float* Wl0 = (const float*)d_in[2];
    const float* bl0 = (const float*)d_in[3];
    const float* Wr0 = (const float*)d_in[4];
    const float* Wl1 = (const float*)d_in[5];
    const float* bl1 = (const float*)d_in[6];
    const float* Wr1 = (const float*)d_in[7];
    const float* Wl2 = (const float*)d_in[8];
    const float* bl2 = (const float*)d_in[9];
    const float* Wr2 = (const float*)d_in[10];
    float* out = (float*)d_out;

    const int N = NN;
    const int E = in_sizes[1] / 2;
    const int* dst = ei;          // edge_index[0]
    const int* src = ei + E;      // edge_index[1]

    char* wsp = (char*)d_ws;
    size_t off = 0;
    auto carve = [&](size_t bytes) {
        char* p = wsp + off;
        off += (bytes + 255) & ~(size_t)255;
        return p;
    };
    int* deg    = (int*)carve((size_t)N * 4);
    int* rowptr = (int*)carve((size_t)(N + 1) * 4);
    int* bsum   = (int*)carve(64 * 4);
    u16* colb   = (u16*)carve((size_t)E * 2);
    u16* xb     = (u16*)carve((size_t)MPAD * 128 * 2);
    u16* aggb   = (u16*)carve((size_t)MPAD * 256 * 2);
    u16* h1b    = (u16*)carve((size_t)MPAD * 256 * 2);
    u16* h2b    = (u16*)carve((size_t)MPAD * 256 * 2);
    u16* Wp0    = (u16*)carve((size_t)256 * 256 * 2);
    u16* Wp1    = (u16*)carve((size_t)256 * 512 * 2);
    u16* Wp2    = (u16*)carve((size_t)256 * 512 * 2);
    // ONE fp8 mirror buffer, time-shared: x8 (prep->agg0), h1b8 (gemm0->agg1),
    // h2b8 (gemm1->agg2) have strictly disjoint lifetimes on the serial stream.
    u8* hb8     = (u8*)carve((size_t)MPAD * 256);
    u8* x8      = hb8;              // only first MPAD*128 bytes used
    (void)ws_size; (void)n_in; (void)out_size;

    hipMemsetAsync(deg, 0, (size_t)N * 4, stream);

    k_count<<<(E + 255) / 256, 256, 0, stream>>>(dst, E, deg);
    int nb = (N + 1023) / 1024;   // 49
    k_scan1<<<nb, 256, 0, stream>>>(deg, N, rowptr, bsum);
    k_scan2<<<1, 64, 0, stream>>>(bsum, nb);
    k_scan3<<<(N + 255) / 256, 256, 0, stream>>>(rowptr, bsum, N, E);

    // fill (deg counts down, u16 col) + castx (bf16+fp8) + weight packs
    k_fcw<<<FCW_TOTAL, 256, 0, stream>>>(dst, src, E, rowptr, deg, colb,
                                         x, xb, x8, Wl0, Wr0, Wp0,
                                         Wl1, Wr1, Wp1, Wl2, Wr2, Wp2);

    const int GB = MPAD / 32;   // 1564 blocks
    const int GA = MPAD / 4;    // 12512 blocks

    // layer 0: K=128
    k_agg8<128><<<GA, 256, 0, stream>>>(x8, rowptr, colb, aggb);
    k_mgemm<128, 0><<<GB, 256, 0, stream>>>(aggb, xb, Wp0, bl0, nullptr, nullptr,
                                            h1b, hb8, nullptr);
    // layer 1: K=256
    k_agg8<256><<<GA, 256, 0, stream>>>(hb8, rowptr, colb, aggb);
    k_mgemm<256, 0><<<GB, 256, 0, stream>>>(aggb, h1b, Wp1, bl1, nullptr, nullptr,
                                            h2b, hb8, nullptr);
    // layer 2: K=256, JK-max epilogue
    k_agg8<256><<<GA, 256, 0, stream>>>(hb8, rowptr, colb, aggb);
    k_mgemm<256, 1><<<GB, 256, 0, stream>>>(aggb, h2b, Wp2, bl2, h1b, h2b,
                                            nullptr, nullptr, out);
}

// Round 16
// 252.830 us; speedup vs baseline: 1.1369x; 1.1369x over previous
//
#include <hip/hip_runtime.h>

#define NN 50000
#define MPAD 50048   // 1564 * 32, padded row count for 32-row GEMM tiles

typedef unsigned short u16;
typedef unsigned int u32;
typedef unsigned char u8;
typedef short s16x8 __attribute__((ext_vector_type(8)));   // 8 bf16 (4 VGPRs)
typedef float f32x4 __attribute__((ext_vector_type(4)));
typedef float f32x2 __attribute__((ext_vector_type(2)));

__device__ inline u16 f2bf(float f) {
    u32 u = __float_as_uint(f);
    u32 r = (u + 0x7FFF + ((u >> 16) & 1)) >> 16;   // RNE
    return (u16)r;
}
__device__ inline float bf2f(u16 s) { return __uint_as_float(((u32)s) << 16); }

// ---- fp8 e4m3 helpers (hw cvt on gfx950; manual fallback) ----
#if __has_builtin(__builtin_amdgcn_cvt_pk_f32_fp8) && __has_builtin(__builtin_amdgcn_cvt_pk_fp8_f32)
#define HW_FP8 1
#endif

__device__ inline float fp8_dec1(u32 b) {   // manual e4m3fn -> f32
    u32 s = (b >> 7) & 1, e = (b >> 3) & 15, m = b & 7;
    float mag = e ? __uint_as_float(((e + 120) << 23) | (m << 20))
                  : (float)m * 0.001953125f;
    return s ? -mag : mag;
}
__device__ inline u8 fp8_enc1(float f) {    // manual f32 -> e4m3fn (RNE)
    u32 u = __float_as_uint(f);
    u32 s = (u >> 31) << 7;
    float a = fabsf(f);
    if (a >= 448.f) return (u8)(s | 0x7E);
    if (a < 0.015625f) {
        u32 m = (u32)__float2int_rn(a * 512.f);
        return (u8)(s | m);
    }
    u32 au = __float_as_uint(a);
    u32 r = au + 0x7FFFF + ((au >> 20) & 1);
    u32 e = (r >> 23) - 120;
    u32 m = (r >> 20) & 7;
    return (u8)(s | (e << 3) | m);
}

__device__ inline void fp8x4_acc(u32 v, float* acc) {
#ifdef HW_FP8
    f32x2 lo = __builtin_amdgcn_cvt_pk_f32_fp8(v, false);
    f32x2 hi = __builtin_amdgcn_cvt_pk_f32_fp8(v, true);
    acc[0] += lo[0]; acc[1] += lo[1]; acc[2] += hi[0]; acc[3] += hi[1];
#else
    acc[0] += fp8_dec1(v & 0xFF);
    acc[1] += fp8_dec1((v >> 8) & 0xFF);
    acc[2] += fp8_dec1((v >> 16) & 0xFF);
    acc[3] += fp8_dec1(v >> 24);
#endif
}
__device__ inline void fp8x2_acc(u32 v, float* acc) {
#ifdef HW_FP8
    f32x2 lo = __builtin_amdgcn_cvt_pk_f32_fp8(v, false);
    acc[0] += lo[0]; acc[1] += lo[1];
#else
    acc[0] += fp8_dec1(v & 0xFF);
    acc[1] += fp8_dec1((v >> 8) & 0xFF);
#endif
}
__device__ inline u32 f32x4_to_fp8(float a, float b, float c, float d) {
#ifdef HW_FP8
    u32 lo = (u32)__builtin_amdgcn_cvt_pk_fp8_f32(a, b, 0, false) & 0xFFFF;
    u32 hi = (u32)__builtin_amdgcn_cvt_pk_fp8_f32(c, d, 0, false) & 0xFFFF;
    return lo | (hi << 16);
#else
    return (u32)fp8_enc1(a) | ((u32)fp8_enc1(b) << 8) |
           ((u32)fp8_enc1(c) << 16) | ((u32)fp8_enc1(d) << 24);
#endif
}

template <typename T>
__device__ inline const __attribute__((address_space(1))) T* as_g(const T* p) {
    return (const __attribute__((address_space(1))) T*)p;
}
template <typename T>
__device__ inline __attribute__((address_space(3))) T* as_l(T* p) {
    return (__attribute__((address_space(3))) T*)p;
}

// ---------------- CSR scans ----------------
__global__ void k_scan1(const int* __restrict__ deg, int n,
                        int* __restrict__ out, int* __restrict__ bsum) {
    __shared__ int s[256];
    int t = threadIdx.x;
    int base = blockIdx.x * 1024;
    int v[4]; int sum = 0;
#pragma unroll
    for (int r = 0; r < 4; r++) {
        int idx = base + t * 4 + r;
        v[r] = (idx < n) ? deg[idx] : 0;
        sum += v[r];
    }
    s[t] = sum; __syncthreads();
    for (int off = 1; off < 256; off <<= 1) {
        int x = (t >= off) ? s[t - off] : 0;
        __syncthreads();
        s[t] += x;
        __syncthreads();
    }
    int excl = s[t] - sum;
    if (t == 255) bsum[blockIdx.x] = s[255];
    int run = excl;
#pragma unroll
    for (int r = 0; r < 4; r++) {
        int idx = base + t * 4 + r;
        if (idx < n) out[idx] = run;
        run += v[r];
    }
}

__global__ void k_scan2(int* __restrict__ bsum, int nb) {
    __shared__ int s[64];
    int t = threadIdx.x;
    int orig = (t < nb) ? bsum[t] : 0;
    s[t] = orig; __syncthreads();
    for (int off = 1; off < 64; off <<= 1) {
        int x = (t >= off) ? s[t - off] : 0;
        __syncthreads();
        s[t] += x;
        __syncthreads();
    }
    if (t < nb) bsum[t] = s[t] - orig;
}

__global__ void k_scan3(int* __restrict__ rowptr, const int* __restrict__ bsum,
                        int n, int E) {
    int i = blockIdx.x * blockDim.x + threadIdx.x;
    if (i < n) rowptr[i] += bsum[i >> 10];
    if (i == 0) rowptr[n] = E;
}

// ------ count (+slot capture) + castx + wpack in ONE launch: the 800K
// atomic-latency-bound count waves hide under 32MB of streaming work ------
__device__ inline void wpack_body(int idx, const float* __restrict__ Wl,
                                  const float* __restrict__ Wr, int K,
                                  u16* __restrict__ Wp) {
    int KC = 2 * K;
    if (idx >= 256 * KC) return;
    int j = idx & 7;
    int l = (idx >> 3) & 63;
    int c = (idx >> 9) & 15;
    int q = idx >> 13;
    int n = c * 16 + (l & 15);
    int k = q * 32 + (l >> 4) * 8 + j;
    float v = (k < K) ? Wl[(size_t)k * 256 + n] : Wr[(size_t)(k - K) * 256 + n];
    Wp[idx] = f2bf(v);
}

#define CNT_BLOCKS ((800000 + 255) / 256)             // 3125
#define CASTX_BLOCKS (MPAD * 128 / 4 / 256)           // 6256
#define CCW_CAST_OFF CNT_BLOCKS
#define CCW_W0_OFF (CCW_CAST_OFF + CASTX_BLOCKS)
#define CCW_W1_OFF (CCW_W0_OFF + 256)
#define CCW_W2_OFF (CCW_W1_OFF + 512)
#define CCW_TOTAL (CCW_W2_OFF + 512)

__global__ void k_ccw(const int* __restrict__ dst, int E, int* __restrict__ deg,
                      int* __restrict__ pos,
                      const float* __restrict__ x, u16* __restrict__ xb,
                      u8* __restrict__ x8,
                      const float* __restrict__ Wl0, const float* __restrict__ Wr0,
                      u16* __restrict__ Wp0,
                      const float* __restrict__ Wl1, const float* __restrict__ Wr1,
                      u16* __restrict__ Wp1,
                      const float* __restrict__ Wl2, const float* __restrict__ Wr2,
                      u16* __restrict__ Wp2) {
    int b = blockIdx.x;
    if (b < CNT_BLOCKS) {
        int e = b * 256 + threadIdx.x;
        if (e < E) {
            int d = dst[e];
            pos[e] = atomicAdd(&deg[d], 1);   // per-edge slot within its node
        }
    } else if (b < CCW_W0_OFF) {
        int i = (b - CCW_CAST_OFF) * 256 + threadIdx.x;
        int idx = i * 4;
        u32 lo = 0, hi = 0, p8 = 0;
        if (idx < NN * 128) {
            float4 v = *reinterpret_cast<const float4*>(x + idx);
            lo = (u32)f2bf(v.x) | ((u32)f2bf(v.y) << 16);
            hi = (u32)f2bf(v.z) | ((u32)f2bf(v.w) << 16);
            p8 = f32x4_to_fp8(v.x, v.y, v.z, v.w);
        }
        uint2 o; o.x = lo; o.y = hi;
        *reinterpret_cast<uint2*>(xb + idx) = o;
        *reinterpret_cast<u32*>(x8 + idx) = p8;
    } else if (b < CCW_W1_OFF) {
        wpack_body((b - CCW_W0_OFF) * 256 + threadIdx.x, Wl0, Wr0, 128, Wp0);
    } else if (b < CCW_W2_OFF) {
        wpack_body((b - CCW_W1_OFF) * 256 + threadIdx.x, Wl1, Wr1, 256, Wp1);
    } else {
        wpack_body((b - CCW_W2_OFF) * 256 + threadIdx.x, Wl2, Wr2, 256, Wp2);
    }
}

// ------ fill: ATOMIC-FREE scatter using precomputed slots ------
__global__ void k_fill(const int* __restrict__ dst, const int* __restrict__ src,
                       const int* __restrict__ pos, int E,
                       const int* __restrict__ rowptr, u16* __restrict__ col) {
    int e = blockIdx.x * 256 + threadIdx.x;
    if (e < E) {
        int d = dst[e];
        col[rowptr[d] + pos[e]] = (u16)src[e];
    }
}

// -------- aggregation (segment mean): fp8 gather -> bf16 out, u16 col --------
template <int D>
__global__ __launch_bounds__(256) void k_agg8(
    const u8* __restrict__ H8, const int* __restrict__ rowptr,
    const u16* __restrict__ col, u16* __restrict__ out) {
    constexpr int PER = D / 64;    // 2 or 4
    int wv = threadIdx.x >> 6, l = threadIdx.x & 63;
    int node = blockIdx.x * 4 + wv;
    if (node >= MPAD) return;
    size_t obase = (size_t)node * D + l * PER;
    if (node >= NN) {
        if (PER == 2) *reinterpret_cast<u32*>(out + obase) = 0;
        else { uint2 z; z.x = 0; z.y = 0; *reinterpret_cast<uint2*>(out + obase) = z; }
        return;
    }
    int beg = rowptr[node], end = rowptr[node + 1];
    float acc[PER];
#pragma unroll
    for (int j = 0; j < PER; j++) acc[j] = 0.f;

    int c = beg;
    if (PER == 4) {
        const int fo = l * 4;
        for (; c + 8 <= end; c += 8) {
            u32 v[8];
#pragma unroll
            for (int u = 0; u < 8; ++u)
                v[u] = *reinterpret_cast<const u32*>(H8 + (size_t)col[c + u] * D + fo);
#pragma unroll
            for (int u = 0; u < 8; ++u) fp8x4_acc(v[u], acc);
        }
        for (; c < end; ++c) {
            u32 v = *reinterpret_cast<const u32*>(H8 + (size_t)col[c] * D + fo);
            fp8x4_acc(v, acc);
        }
    } else {
        const int fo = l * 2;
        for (; c + 8 <= end; c += 8) {
            u16 v[8];
#pragma unroll
            for (int u = 0; u < 8; ++u)
                v[u] = *reinterpret_cast<const u16*>(H8 + (size_t)col[c + u] * D + fo);
#pragma unroll
            for (int u = 0; u < 8; ++u) fp8x2_acc((u32)v[u], acc);
        }
        for (; c < end; ++c) {
            u16 v = *reinterpret_cast<const u16*>(H8 + (size_t)col[c] * D + fo);
            fp8x2_acc((u32)v, acc);
        }
    }
    float inv = 1.f / fmaxf((float)(end - beg), 1.f);
    if (PER == 2) {
        u32 o = (u32)f2bf(acc[0] * inv) | ((u32)f2bf(acc[1] * inv) << 16);
        *reinterpret_cast<u32*>(out + obase) = o;
    } else {
        uint2 o;
        o.x = (u32)f2bf(acc[0] * inv) | ((u32)f2bf(acc[1] * inv) << 16);
        o.y = (u32)f2bf(acc[2] * inv) | ((u32)f2bf(acc[3] * inv) << 16);
        *reinterpret_cast<uint2*>(out + obase) = o;
    }
}

// ---------------- MFMA GEMM (round-14 structure — best measured) ----------------
// BM=32 (1564 blocks). A tile LDS dbuf (global_load_lds, XOR swizzle); B from
// packed Wp direct-to-registers, reg-double-buffered. Epilogue goes through LDS
// and writes fully-coalesced dwordx4 -> no sector write amplification.
template <int K, int MODE>   // MODE 0: relu -> bf16+fp8; MODE 1: JK-max -> f32
__global__ __launch_bounds__(256) void k_mgemm(
    const u16* __restrict__ Aagg, const u16* __restrict__ Ah,
    const u16* __restrict__ Wp, const float* __restrict__ bias,
    const u16* __restrict__ h1b, const u16* __restrict__ h2b,
    u16* __restrict__ outb, u8* __restrict__ out8, float* __restrict__ outf) {
    constexpr int KC = 2 * K;
    constexpr int NSTEP = KC / 64;     // 4 or 8, always even
    __shared__ u16 sA[2 * 32 * 64];    // 8KB, double-buffered A tile
    __shared__ char sEpi[32 * 264 * 2];// 16.9KB epilogue staging
    int tid = threadIdx.x;
    int w = tid >> 6, l = tid & 63;
    int row0 = blockIdx.x * 32;
    int lr = l & 15, lk = l >> 4;

    f32x4 acc[2][4];
#pragma unroll
    for (int m = 0; m < 2; m++)
#pragma unroll
        for (int n = 0; n < 4; n++) acc[m][n] = (f32x4){0.f, 0.f, 0.f, 0.f};

    auto stageA = [&](int buf, int st) {
        int kk = st * 64;
        const u16* Ab = (kk < K) ? Aagg : Ah;
        int koff = (kk < K) ? kk : kk - K;
        int r = tid >> 3, c = tid & 7;       // 32 rows x 8 chunks = 256
        int g = c ^ (r & 7);
        const u16* ga = Ab + (size_t)(row0 + r) * K + koff + g * 8;
        u16* lb = sA + buf * 2048 + (size_t)(tid & ~63) * 8;
        __builtin_amdgcn_global_load_lds(as_g(ga), as_l(lb), 16, 0, 0);
    };

    auto loadB = [&](s16x8 (&bv)[2][4], int st) {
#pragma unroll
        for (int kk2 = 0; kk2 < 2; ++kk2) {
            int q = st * 2 + kk2;
#pragma unroll
            for (int n = 0; n < 4; ++n) {
                const u16* gb = Wp + ((size_t)(q * 16 + w * 4 + n) * 64 + l) * 8;
                bv[kk2][n] = *reinterpret_cast<const s16x8*>(gb);
            }
        }
    };

    s16x8 bv0[2][4], bv1[2][4];
    loadB(bv0, 0);
    stageA(0, 0);

    auto body = [&](int st, s16x8 (&bvUse)[2][4], s16x8 (&bvNext)[2][4]) {
        __syncthreads();                   // A buf (st&1) staged (vmcnt drained)
        if (st + 1 < NSTEP) {
            loadB(bvNext, st + 1);         // prefetch next B into regs
            stageA((st + 1) & 1, st + 1);  // prefetch next A tile into LDS
        }
        const char* sAb = reinterpret_cast<const char*>(sA) + (st & 1) * 4096;
#pragma unroll
        for (int kk2 = 0; kk2 < 2; ++kk2) {
            s16x8 av[2];
#pragma unroll
            for (int m = 0; m < 2; ++m) {
                int off = (m * 16 + lr) * 128 + (((kk2 * 4 + lk) ^ (lr & 7)) << 4);
                av[m] = *reinterpret_cast<const s16x8*>(sAb + off);
            }
#pragma unroll
            for (int m = 0; m < 2; ++m)
#pragma unroll
                for (int n = 0; n < 4; ++n)
                    acc[m][n] = __builtin_amdgcn_mfma_f32_16x16x32_bf16(
                        av[m], bvUse[kk2][n], acc[m][n], 0, 0, 0);
        }
    };

    for (int st = 0; st < NSTEP; st += 2) {
        body(st, bv0, bv1);
        body(st + 1, bv1, bv0);
    }

    float bb[4];
#pragma unroll
    for (int n = 0; n < 4; ++n) bb[n] = bias[w * 64 + n * 16 + lr];

    if (MODE == 0) {
        u16* sE = (u16*)sEpi;              // [32][264] bf16, padded stride
#pragma unroll
        for (int m = 0; m < 2; ++m)
#pragma unroll
            for (int n = 0; n < 4; ++n) {
                int colx = w * 64 + n * 16 + lr;
#pragma unroll
                for (int i = 0; i < 4; ++i) {
                    int row = m * 16 + lk * 4 + i;
                    float z = fmaxf(acc[m][n][i] + bb[n], 0.f);
                    sE[row * 264 + colx] = f2bf(z);
                }
            }
        __syncthreads();
#pragma unroll
        for (int j = 0; j < 4; ++j) {
            int idx = j * 256 + tid;
            int r = idx >> 5;              // 0..31
            int cp = (idx & 31) * 8;       // col start (8 bf16 = 16B)
            uint4 v = *reinterpret_cast<const uint4*>(sE + r * 264 + cp);
            size_t go = (size_t)(row0 + r) * 256 + cp;
            *reinterpret_cast<uint4*>(outb + go) = v;
            u32 l8 = f32x4_to_fp8(bf2f((u16)(v.x & 0xFFFF)), bf2f((u16)(v.x >> 16)),
                                  bf2f((u16)(v.y & 0xFFFF)), bf2f((u16)(v.y >> 16)));
            u32 h8 = f32x4_to_fp8(bf2f((u16)(v.z & 0xFFFF)), bf2f((u16)(v.z >> 16)),
                                  bf2f((u16)(v.w & 0xFFFF)), bf2f((u16)(v.w >> 16)));
            uint2 o8; o8.x = l8; o8.y = h8;
            *reinterpret_cast<uint2*>(out8 + go) = o8;
        }
    } else {
        float* sEf = (float*)sEpi;         // [16][260] f32 per half-tile
#pragma unroll
        for (int m = 0; m < 2; ++m) {
#pragma unroll
            for (int n = 0; n < 4; ++n) {
                int colx = w * 64 + n * 16 + lr;
#pragma unroll
                for (int i = 0; i < 4; ++i) {
                    int row = row0 + m * 16 + lk * 4 + i;
                    size_t o = (size_t)row * 256 + colx;
                    float z = acc[m][n][i] + bb[n];
                    z = fmaxf(z, fmaxf(bf2f(h1b[o]), bf2f(h2b[o])));
                    sEf[(lk * 4 + i) * 260 + colx] = z;
                }
            }
            __syncthreads();
#pragma unroll
            for (int j = 0; j < 4; ++j) {
                int idx = j * 256 + tid;
                int r = idx >> 6;          // 0..15
                int cp = (idx & 63) * 4;   // 4 floats = 16B
                int grow = row0 + m * 16 + r;
                if (grow < NN) {
                    uint4 v = *reinterpret_cast<const uint4*>(sEf + r * 260 + cp);
                    *reinterpret_cast<uint4*>(outf + (size_t)grow * 256 + cp) = v;
                }
            }
            __syncthreads();               // WAR before next half-tile
        }
    }
}

extern "C" void kernel_launch(void* const* d_in, const int* in_sizes, int n_in,
                              void* d_out, int out_size, void* d_ws, size_t ws_size,
                              hipStream_t stream) {
    const float* x   = (const float*)d_in[0];
    const int*   ei  = (const int*)d_in[1];
    const float* Wl0 = (const float*)d_in[2];
    const float* bl0 = (const float*)d_in[3];
    const float* Wr0 = (const float*)d_in[4];
    const float* Wl1 = (const float*)d_in[5];
    const float* bl1 = (const float*)d_in[6];
    const float* Wr1 = (const float*)d_in[7];
    const float* Wl2 = (const float*)d_in[8];
    const float* bl2 = (const float*)d_in[9];
    const float* Wr2 = (const float*)d_in[10];
    float* out = (float*)d_out;

    const int N = NN;
    const int E = in_sizes[1] / 2;
    const int* dst = ei;          // edge_index[0]
    const int* src = ei + E;      // edge_index[1]

    char* wsp = (char*)d_ws;
    size_t off = 0;
    auto carve = [&](size_t bytes) {
        char* p = wsp + off;
        off += (bytes + 255) & ~(size_t)255;
        return p;
    };
    int* deg    = (int*)carve((size_t)N * 4);
    int* rowptr = (int*)carve((size_t)(N + 1) * 4);
    int* bsum   = (int*)carve(64 * 4);
    int* pos    = (int*)carve((size_t)E * 4);
    u16* colb   = (u16*)carve((size_t)E * 2);
    u16* xb     = (u16*)carve((size_t)MPAD * 128 * 2);
    u16* aggb   = (u16*)carve((size_t)MPAD * 256 * 2);
    u16* h1b    = (u16*)carve((size_t)MPAD * 256 * 2);
    u16* h2b    = (u16*)carve((size_t)MPAD * 256 * 2);
    u16* Wp0    = (u16*)carve((size_t)256 * 256 * 2);
    u16* Wp1    = (u16*)carve((size_t)256 * 512 * 2);
    u16* Wp2    = (u16*)carve((size_t)256 * 512 * 2);
    // ONE fp8 mirror buffer, time-shared: x8 (ccw->agg0), h1b8 (gemm0->agg1),
    // h2b8 (gemm1->agg2) have strictly disjoint lifetimes on the serial stream.
    u8* hb8     = (u8*)carve((size_t)MPAD * 256);
    u8* x8      = hb8;              // only first MPAD*128 bytes used
    (void)ws_size; (void)n_in; (void)out_size;

    hipMemsetAsync(deg, 0, (size_t)N * 4, stream);

    // count (captures per-edge slot) + castx (bf16+fp8) + weight packs
    k_ccw<<<CCW_TOTAL, 256, 0, stream>>>(dst, E, deg, pos,
                                         x, xb, x8, Wl0, Wr0, Wp0,
                                         Wl1, Wr1, Wp1, Wl2, Wr2, Wp2);

    int nb = (N + 1023) / 1024;   // 49
    k_scan1<<<nb, 256, 0, stream>>>(deg, N, rowptr, bsum);
    k_scan2<<<1, 64, 0, stream>>>(bsum, nb);
    k_scan3<<<(N + 255) / 256, 256, 0, stream>>>(rowptr, bsum, N, E);

    // atomic-free scatter fill
    k_fill<<<CNT_BLOCKS, 256, 0, stream>>>(dst, src, pos, E, rowptr, colb);

    const int GB = MPAD / 32;   // 1564 blocks
    const int GA = MPAD / 4;    // 12512 blocks

    // layer 0: K=128
    k_agg8<128><<<GA, 256, 0, stream>>>(x8, rowptr, colb, aggb);
    k_mgemm<128, 0><<<GB, 256, 0, stream>>>(aggb, xb, Wp0, bl0, nullptr, nullptr,
                                            h1b, hb8, nullptr);
    // layer 1: K=256
    k_agg8<256><<<GA, 256, 0, stream>>>(hb8, rowptr, colb, aggb);
    k_mgemm<256, 0><<<GB, 256, 0, stream>>>(aggb, h1b, Wp1, bl1, nullptr, nullptr,
                                            h2b, hb8, nullptr);
    // layer 2: K=256, JK-max epilogue
    k_agg8<256><<<GA, 256, 0, stream>>>(hb8, rowptr, colb, aggb);
    k_mgemm<256, 1><<<GB, 256, 0, stream>>>(aggb, h2b, Wp2, bl2, h1b, h2b,
                                            nullptr, nullptr, out);
}

// Round 17
// 250.485 us; speedup vs baseline: 1.1476x; 1.0094x over previous
//
#include <hip/hip_runtime.h>

#define NN 50000
#define MPAD 50048   // 1564 * 32, padded row count for 32-row GEMM tiles

typedef unsigned short u16;
typedef unsigned int u32;
typedef unsigned char u8;
typedef short s16x8 __attribute__((ext_vector_type(8)));   // 8 bf16 (4 VGPRs)
typedef float f32x4 __attribute__((ext_vector_type(4)));
typedef float f32x2 __attribute__((ext_vector_type(2)));

__device__ inline u16 f2bf(float f) {
    u32 u = __float_as_uint(f);
    u32 r = (u + 0x7FFF + ((u >> 16) & 1)) >> 16;   // RNE
    return (u16)r;
}
__device__ inline float bf2f(u16 s) { return __uint_as_float(((u32)s) << 16); }

// ---- fp8 e4m3 helpers (hw cvt on gfx950; manual fallback) ----
#if __has_builtin(__builtin_amdgcn_cvt_pk_f32_fp8) && __has_builtin(__builtin_amdgcn_cvt_pk_fp8_f32)
#define HW_FP8 1
#endif

__device__ inline float fp8_dec1(u32 b) {   // manual e4m3fn -> f32
    u32 s = (b >> 7) & 1, e = (b >> 3) & 15, m = b & 7;
    float mag = e ? __uint_as_float(((e + 120) << 23) | (m << 20))
                  : (float)m * 0.001953125f;
    return s ? -mag : mag;
}
__device__ inline u8 fp8_enc1(float f) {    // manual f32 -> e4m3fn (RNE)
    u32 u = __float_as_uint(f);
    u32 s = (u >> 31) << 7;
    float a = fabsf(f);
    if (a >= 448.f) return (u8)(s | 0x7E);
    if (a < 0.015625f) {
        u32 m = (u32)__float2int_rn(a * 512.f);
        return (u8)(s | m);
    }
    u32 au = __float_as_uint(a);
    u32 r = au + 0x7FFFF + ((au >> 20) & 1);
    u32 e = (r >> 23) - 120;
    u32 m = (r >> 20) & 7;
    return (u8)(s | (e << 3) | m);
}

__device__ inline void fp8x4_acc(u32 v, float* acc) {
#ifdef HW_FP8
    f32x2 lo = __builtin_amdgcn_cvt_pk_f32_fp8(v, false);
    f32x2 hi = __builtin_amdgcn_cvt_pk_f32_fp8(v, true);
    acc[0] += lo[0]; acc[1] += lo[1]; acc[2] += hi[0]; acc[3] += hi[1];
#else
    acc[0] += fp8_dec1(v & 0xFF);
    acc[1] += fp8_dec1((v >> 8) & 0xFF);
    acc[2] += fp8_dec1((v >> 16) & 0xFF);
    acc[3] += fp8_dec1(v >> 24);
#endif
}
__device__ inline void fp8x2_acc(u32 v, float* acc) {
#ifdef HW_FP8
    f32x2 lo = __builtin_amdgcn_cvt_pk_f32_fp8(v, false);
    acc[0] += lo[0]; acc[1] += lo[1];
#else
    acc[0] += fp8_dec1(v & 0xFF);
    acc[1] += fp8_dec1((v >> 8) & 0xFF);
#endif
}
__device__ inline u32 f32x4_to_fp8(float a, float b, float c, float d) {
#ifdef HW_FP8
    u32 lo = (u32)__builtin_amdgcn_cvt_pk_fp8_f32(a, b, 0, false) & 0xFFFF;
    u32 hi = (u32)__builtin_amdgcn_cvt_pk_fp8_f32(c, d, 0, false) & 0xFFFF;
    return lo | (hi << 16);
#else
    return (u32)fp8_enc1(a) | ((u32)fp8_enc1(b) << 8) |
           ((u32)fp8_enc1(c) << 16) | ((u32)fp8_enc1(d) << 24);
#endif
}

template <typename T>
__device__ inline const __attribute__((address_space(1))) T* as_g(const T* p) {
    return (const __attribute__((address_space(1))) T*)p;
}
template <typename T>
__device__ inline __attribute__((address_space(3))) T* as_l(T* p) {
    return (__attribute__((address_space(3))) T*)p;
}

// ---------------- CSR scans ----------------
__global__ void k_scan1(const int* __restrict__ deg, int n,
                        int* __restrict__ out, int* __restrict__ bsum) {
    __shared__ int s[256];
    int t = threadIdx.x;
    int base = blockIdx.x * 1024;
    int v[4]; int sum = 0;
#pragma unroll
    for (int r = 0; r < 4; r++) {
        int idx = base + t * 4 + r;
        v[r] = (idx < n) ? deg[idx] : 0;
        sum += v[r];
    }
    s[t] = sum; __syncthreads();
    for (int off = 1; off < 256; off <<= 1) {
        int x = (t >= off) ? s[t - off] : 0;
        __syncthreads();
        s[t] += x;
        __syncthreads();
    }
    int excl = s[t] - sum;
    if (t == 255) bsum[blockIdx.x] = s[255];
    int run = excl;
#pragma unroll
    for (int r = 0; r < 4; r++) {
        int idx = base + t * 4 + r;
        if (idx < n) out[idx] = run;
        run += v[r];
    }
}

__global__ void k_scan2(int* __restrict__ bsum, int nb) {
    __shared__ int s[64];
    int t = threadIdx.x;
    int orig = (t < nb) ? bsum[t] : 0;
    s[t] = orig; __syncthreads();
    for (int off = 1; off < 64; off <<= 1) {
        int x = (t >= off) ? s[t - off] : 0;
        __syncthreads();
        s[t] += x;
        __syncthreads();
    }
    if (t < nb) bsum[t] = s[t] - orig;
}

__global__ void k_scan3(int* __restrict__ rowptr, const int* __restrict__ bsum,
                        int n, int E) {
    int i = blockIdx.x * blockDim.x + threadIdx.x;
    if (i < n) rowptr[i] += bsum[i >> 10];
    if (i == 0) rowptr[n] = E;
}

// ------ count (+slot capture, 8 edges/thread for atomic MLP) + castx + wpack ------
__device__ inline void wpack_body(int idx, const float* __restrict__ Wl,
                                  const float* __restrict__ Wr, int K,
                                  u16* __restrict__ Wp) {
    int KC = 2 * K;
    if (idx >= 256 * KC) return;
    int j = idx & 7;
    int l = (idx >> 3) & 63;
    int c = (idx >> 9) & 15;
    int q = idx >> 13;
    int n = c * 16 + (l & 15);
    int k = q * 32 + (l >> 4) * 8 + j;
    float v = (k < K) ? Wl[(size_t)k * 256 + n] : Wr[(size_t)(k - K) * 256 + n];
    Wp[idx] = f2bf(v);
}

#define CNT_BLOCKS ((800000 + 2047) / 2048)           // 391 (8 edges/thread)
#define CASTX_BLOCKS (MPAD * 128 / 4 / 256)           // 6256
#define CCW_CAST_OFF CNT_BLOCKS
#define CCW_W0_OFF (CCW_CAST_OFF + CASTX_BLOCKS)
#define CCW_W1_OFF (CCW_W0_OFF + 256)
#define CCW_W2_OFF (CCW_W1_OFF + 512)
#define CCW_TOTAL (CCW_W2_OFF + 512)

__global__ void k_ccw(const int* __restrict__ dst, int E, int* __restrict__ deg,
                      u16* __restrict__ pos,
                      const float* __restrict__ x, u16* __restrict__ xb,
                      u8* __restrict__ x8,
                      const float* __restrict__ Wl0, const float* __restrict__ Wr0,
                      u16* __restrict__ Wp0,
                      const float* __restrict__ Wl1, const float* __restrict__ Wr1,
                      u16* __restrict__ Wp1,
                      const float* __restrict__ Wl2, const float* __restrict__ Wr2,
                      u16* __restrict__ Wp2) {
    int b = blockIdx.x;
    if (b < CNT_BLOCKS) {
        int base = b * 2048 + threadIdx.x;
#pragma unroll
        for (int j = 0; j < 8; ++j) {      // 8 independent atomics in flight
            int e = base + j * 256;
            if (e < E) {
                int d = dst[e];
                pos[e] = (u16)atomicAdd(&deg[d], 1);
            }
        }
    } else if (b < CCW_W0_OFF) {
        int i = (b - CCW_CAST_OFF) * 256 + threadIdx.x;
        int idx = i * 4;
        u32 lo = 0, hi = 0, p8 = 0;
        if (idx < NN * 128) {
            float4 v = *reinterpret_cast<const float4*>(x + idx);
            lo = (u32)f2bf(v.x) | ((u32)f2bf(v.y) << 16);
            hi = (u32)f2bf(v.z) | ((u32)f2bf(v.w) << 16);
            p8 = f32x4_to_fp8(v.x, v.y, v.z, v.w);
        }
        uint2 o; o.x = lo; o.y = hi;
        *reinterpret_cast<uint2*>(xb + idx) = o;
        *reinterpret_cast<u32*>(x8 + idx) = p8;
    } else if (b < CCW_W1_OFF) {
        wpack_body((b - CCW_W0_OFF) * 256 + threadIdx.x, Wl0, Wr0, 128, Wp0);
    } else if (b < CCW_W2_OFF) {
        wpack_body((b - CCW_W1_OFF) * 256 + threadIdx.x, Wl1, Wr1, 256, Wp1);
    } else {
        wpack_body((b - CCW_W2_OFF) * 256 + threadIdx.x, Wl2, Wr2, 256, Wp2);
    }
}

// ------ fill: ATOMIC-FREE scatter, 8 edges/thread ------
__global__ void k_fill(const int* __restrict__ dst, const int* __restrict__ src,
                       const u16* __restrict__ pos, int E,
                       const int* __restrict__ rowptr, u16* __restrict__ col) {
    int base = blockIdx.x * 2048 + threadIdx.x;
#pragma unroll
    for (int j = 0; j < 8; ++j) {
        int e = base + j * 256;
        if (e < E) {
            int d = dst[e];
            col[rowptr[d] + pos[e]] = (u16)src[e];
        }
    }
}

// -------- aggregation (segment mean): fp8 gather -> bf16 out, u16 col --------
template <int D>
__global__ __launch_bounds__(256) void k_agg8(
    const u8* __restrict__ H8, const int* __restrict__ rowptr,
    const u16* __restrict__ col, u16* __restrict__ out) {
    constexpr int PER = D / 64;    // 2 or 4
    int wv = threadIdx.x >> 6, l = threadIdx.x & 63;
    int node = blockIdx.x * 4 + wv;
    if (node >= MPAD) return;
    size_t obase = (size_t)node * D + l * PER;
    if (node >= NN) {
        if (PER == 2) *reinterpret_cast<u32*>(out + obase) = 0;
        else { uint2 z; z.x = 0; z.y = 0; *reinterpret_cast<uint2*>(out + obase) = z; }
        return;
    }
    int beg = rowptr[node], end = rowptr[node + 1];
    float acc[PER];
#pragma unroll
    for (int j = 0; j < PER; j++) acc[j] = 0.f;

    int c = beg;
    if (PER == 4) {
        const int fo = l * 4;
        for (; c + 8 <= end; c += 8) {
            u32 v[8];
#pragma unroll
            for (int u = 0; u < 8; ++u)
                v[u] = *reinterpret_cast<const u32*>(H8 + (size_t)col[c + u] * D + fo);
#pragma unroll
            for (int u = 0; u < 8; ++u) fp8x4_acc(v[u], acc);
        }
        for (; c < end; ++c) {
            u32 v = *reinterpret_cast<const u32*>(H8 + (size_t)col[c] * D + fo);
            fp8x4_acc(v, acc);
        }
    } else {
        const int fo = l * 2;
        for (; c + 8 <= end; c += 8) {
            u16 v[8];
#pragma unroll
            for (int u = 0; u < 8; ++u)
                v[u] = *reinterpret_cast<const u16*>(H8 + (size_t)col[c + u] * D + fo);
#pragma unroll
            for (int u = 0; u < 8; ++u) fp8x2_acc((u32)v[u], acc);
        }
        for (; c < end; ++c) {
            u16 v = *reinterpret_cast<const u16*>(H8 + (size_t)col[c] * D + fo);
            fp8x2_acc((u32)v, acc);
        }
    }
    float inv = 1.f / fmaxf((float)(end - beg), 1.f);
    if (PER == 2) {
        u32 o = (u32)f2bf(acc[0] * inv) | ((u32)f2bf(acc[1] * inv) << 16);
        *reinterpret_cast<u32*>(out + obase) = o;
    } else {
        uint2 o;
        o.x = (u32)f2bf(acc[0] * inv) | ((u32)f2bf(acc[1] * inv) << 16);
        o.y = (u32)f2bf(acc[2] * inv) | ((u32)f2bf(acc[3] * inv) << 16);
        *reinterpret_cast<uint2*>(out + obase) = o;
    }
}

// ---------------- MFMA GEMM (round-14 structure — best measured) ----------------
template <int K, int MODE>   // MODE 0: relu -> bf16+fp8; MODE 1: JK-max -> f32
__global__ __launch_bounds__(256) void k_mgemm(
    const u16* __restrict__ Aagg, const u16* __restrict__ Ah,
    const u16* __restrict__ Wp, const float* __restrict__ bias,
    const u16* __restrict__ h1b, const u16* __restrict__ h2b,
    u16* __restrict__ outb, u8* __restrict__ out8, float* __restrict__ outf) {
    constexpr int KC = 2 * K;
    constexpr int NSTEP = KC / 64;     // 4 or 8, always even
    __shared__ u16 sA[2 * 32 * 64];    // 8KB, double-buffered A tile
    __shared__ char sEpi[32 * 264 * 2];// 16.9KB epilogue staging
    int tid = threadIdx.x;
    int w = tid >> 6, l = tid & 63;
    int row0 = blockIdx.x * 32;
    int lr = l & 15, lk = l >> 4;

    f32x4 acc[2][4];
#pragma unroll
    for (int m = 0; m < 2; m++)
#pragma unroll
        for (int n = 0; n < 4; n++) acc[m][n] = (f32x4){0.f, 0.f, 0.f, 0.f};

    auto stageA = [&](int buf, int st) {
        int kk = st * 64;
        const u16* Ab = (kk < K) ? Aagg : Ah;
        int koff = (kk < K) ? kk : kk - K;
        int r = tid >> 3, c = tid & 7;       // 32 rows x 8 chunks = 256
        int g = c ^ (r & 7);
        const u16* ga = Ab + (size_t)(row0 + r) * K + koff + g * 8;
        u16* lb = sA + buf * 2048 + (size_t)(tid & ~63) * 8;
        __builtin_amdgcn_global_load_lds(as_g(ga), as_l(lb), 16, 0, 0);
    };

    auto loadB = [&](s16x8 (&bv)[2][4], int st) {
#pragma unroll
        for (int kk2 = 0; kk2 < 2; ++kk2) {
            int q = st * 2 + kk2;
#pragma unroll
            for (int n = 0; n < 4; ++n) {
                const u16* gb = Wp + ((size_t)(q * 16 + w * 4 + n) * 64 + l) * 8;
                bv[kk2][n] = *reinterpret_cast<const s16x8*>(gb);
            }
        }
    };

    s16x8 bv0[2][4], bv1[2][4];
    loadB(bv0, 0);
    stageA(0, 0);

    auto body = [&](int st, s16x8 (&bvUse)[2][4], s16x8 (&bvNext)[2][4]) {
        __syncthreads();                   // A buf (st&1) staged (vmcnt drained)
        if (st + 1 < NSTEP) {
            loadB(bvNext, st + 1);         // prefetch next B into regs
            stageA((st + 1) & 1, st + 1);  // prefetch next A tile into LDS
        }
        const char* sAb = reinterpret_cast<const char*>(sA) + (st & 1) * 4096;
#pragma unroll
        for (int kk2 = 0; kk2 < 2; ++kk2) {
            s16x8 av[2];
#pragma unroll
            for (int m = 0; m < 2; ++m) {
                int off = (m * 16 + lr) * 128 + (((kk2 * 4 + lk) ^ (lr & 7)) << 4);
                av[m] = *reinterpret_cast<const s16x8*>(sAb + off);
            }
#pragma unroll
            for (int m = 0; m < 2; ++m)
#pragma unroll
                for (int n = 0; n < 4; ++n)
                    acc[m][n] = __builtin_amdgcn_mfma_f32_16x16x32_bf16(
                        av[m], bvUse[kk2][n], acc[m][n], 0, 0, 0);
        }
    };

    for (int st = 0; st < NSTEP; st += 2) {
        body(st, bv0, bv1);
        body(st + 1, bv1, bv0);
    }

    float bb[4];
#pragma unroll
    for (int n = 0; n < 4; ++n) bb[n] = bias[w * 64 + n * 16 + lr];

    if (MODE == 0) {
        u16* sE = (u16*)sEpi;              // [32][264] bf16, padded stride
#pragma unroll
        for (int m = 0; m < 2; ++m)
#pragma unroll
            for (int n = 0; n < 4; ++n) {
                int colx = w * 64 + n * 16 + lr;
#pragma unroll
                for (int i = 0; i < 4; ++i) {
                    int row = m * 16 + lk * 4 + i;
                    float z = fmaxf(acc[m][n][i] + bb[n], 0.f);
                    sE[row * 264 + colx] = f2bf(z);
                }
            }
        __syncthreads();
#pragma unroll
        for (int j = 0; j < 4; ++j) {
            int idx = j * 256 + tid;
            int r = idx >> 5;              // 0..31
            int cp = (idx & 31) * 8;       // col start (8 bf16 = 16B)
            uint4 v = *reinterpret_cast<const uint4*>(sE + r * 264 + cp);
            size_t go = (size_t)(row0 + r) * 256 + cp;
            *reinterpret_cast<uint4*>(outb + go) = v;
            u32 l8 = f32x4_to_fp8(bf2f((u16)(v.x & 0xFFFF)), bf2f((u16)(v.x >> 16)),
                                  bf2f((u16)(v.y & 0xFFFF)), bf2f((u16)(v.y >> 16)));
            u32 h8 = f32x4_to_fp8(bf2f((u16)(v.z & 0xFFFF)), bf2f((u16)(v.z >> 16)),
                                  bf2f((u16)(v.w & 0xFFFF)), bf2f((u16)(v.w >> 16)));
            uint2 o8; o8.x = l8; o8.y = h8;
            *reinterpret_cast<uint2*>(out8 + go) = o8;
        }
    } else {
        float* sEf = (float*)sEpi;         // [16][260] f32 per half-tile
#pragma unroll
        for (int m = 0; m < 2; ++m) {
#pragma unroll
            for (int n = 0; n < 4; ++n) {
                int colx = w * 64 + n * 16 + lr;
#pragma unroll
                for (int i = 0; i < 4; ++i) {
                    int row = row0 + m * 16 + lk * 4 + i;
                    size_t o = (size_t)row * 256 + colx;
                    float z = acc[m][n][i] + bb[n];
                    z = fmaxf(z, fmaxf(bf2f(h1b[o]), bf2f(h2b[o])));
                    sEf[(lk * 4 + i) * 260 + colx] = z;
                }
            }
            __syncthreads();
#pragma unroll
            for (int j = 0; j < 4; ++j) {
                int idx = j * 256 + tid;
                int r = idx >> 6;          // 0..15
                int cp = (idx & 63) * 4;   // 4 floats = 16B
                int grow = row0 + m * 16 + r;
                if (grow < NN) {
                    uint4 v = *reinterpret_cast<const uint4*>(sEf + r * 260 + cp);
                    *reinterpret_cast<uint4*>(outf + (size_t)grow * 256 + cp) = v;
                }
            }
            __syncthreads();               // WAR before next half-tile
        }
    }
}

extern "C" void kernel_launch(void* const* d_in, const int* in_sizes, int n_in,
                              void* d_out, int out_size, void* d_ws, size_t ws_size,
                              hipStream_t stream) {
    const float* x   = (const float*)d_in[0];
    const int*   ei  = (const int*)d_in[1];
    const float* Wl0 = (const float*)d_in[2];
    const float* bl0 = (const float*)d_in[3];
    const float* Wr0 = (const float*)d_in[4];
    const float* Wl1 = (const float*)d_in[5];
    const float* bl1 = (const float*)d_in[6];
    const float* Wr1 = (const float*)d_in[7];
    const float* Wl2 = (const float*)d_in[8];
    const float* bl2 = (const float*)d_in[9];
    const float* Wr2 = (const float*)d_in[10];
    float* out = (float*)d_out;

    const int N = NN;
    const int E = in_sizes[1] / 2;
    const int* dst = ei;          // edge_index[0]
    const int* src = ei + E;      // edge_index[1]

    char* wsp = (char*)d_ws;
    size_t off = 0;
    auto carve = [&](size_t bytes) {
        char* p = wsp + off;
        off += (bytes + 255) & ~(size_t)255;
        return p;
    };
    int* deg    = (int*)carve((size_t)N * 4);
    int* rowptr = (int*)carve((size_t)(N + 1) * 4);
    int* bsum   = (int*)carve(64 * 4);
    u16* pos    = (u16*)carve((size_t)E * 2);
    u16* colb   = (u16*)carve((size_t)E * 2);
    u16* xb     = (u16*)carve((size_t)MPAD * 128 * 2);
    u16* aggb   = (u16*)carve((size_t)MPAD * 256 * 2);
    u16* h1b    = (u16*)carve((size_t)MPAD * 256 * 2);
    u16* h2b    = (u16*)carve((size_t)MPAD * 256 * 2);
    u16* Wp0    = (u16*)carve((size_t)256 * 256 * 2);
    u16* Wp1    = (u16*)carve((size_t)256 * 512 * 2);
    u16* Wp2    = (u16*)carve((size_t)256 * 512 * 2);
    // ONE fp8 mirror buffer, time-shared: x8 (ccw->agg0), h1b8 (gemm0->agg1),
    // h2b8 (gemm1->agg2) have strictly disjoint lifetimes on the serial stream.
    u8* hb8     = (u8*)carve((size_t)MPAD * 256);
    u8* x8      = hb8;              // only first MPAD*128 bytes used
    (void)ws_size; (void)n_in; (void)out_size;

    hipMemsetAsync(deg, 0, (size_t)N * 4, stream);

    // count (8 edges/thread, captures per-edge slot) + castx + weight packs
    k_ccw<<<CCW_TOTAL, 256, 0, stream>>>(dst, E, deg, pos,
                                         x, xb, x8, Wl0, Wr0, Wp0,
                                         Wl1, Wr1, Wp1, Wl2, Wr2, Wp2);

    int nb = (N + 1023) / 1024;   // 49
    k_scan1<<<nb, 256, 0, stream>>>(deg, N, rowptr, bsum);
    k_scan2<<<1, 64, 0, stream>>>(bsum, nb);
    k_scan3<<<(N + 255) / 256, 256, 0, stream>>>(rowptr, bsum, N, E);

    // atomic-free scatter fill (8 edges/thread)
    k_fill<<<CNT_BLOCKS, 256, 0, stream>>>(dst, src, pos, E, rowptr, colb);

    const int GB = MPAD / 32;   // 1564 blocks
    const int GA = MPAD / 4;    // 12512 blocks

    // layer 0: K=128
    k_agg8<128><<<GA, 256, 0, stream>>>(x8, rowptr, colb, aggb);
    k_mgemm<128, 0><<<GB, 256, 0, stream>>>(aggb, xb, Wp0, bl0, nullptr, nullptr,
                                            h1b, hb8, nullptr);
    // layer 1: K=256
    k_agg8<256><<<GA, 256, 0, stream>>>(hb8, rowptr, colb, aggb);
    k_mgemm<256, 0><<<GB, 256, 0, stream>>>(aggb, h1b, Wp1, bl1, nullptr, nullptr,
                                            h2b, hb8, nullptr);
    // layer 2: K=256, JK-max epilogue
    k_agg8<256><<<GA, 256, 0, stream>>>(hb8, rowptr, colb, aggb);
    k_mgemm<256, 1><<<GB, 256, 0, stream>>>(aggb, h2b, Wp2, bl2, h1b, h2b,
                                            nullptr, nullptr, out);
}